// Round 1
// baseline (616.707 us; speedup 1.0000x reference)
//
#include <hip/hip_runtime.h>
#include <math.h>

#define NN 50000
#define NE 800000
#define NBLK 49   // ceil(NN/1024)

// ---------------- degree / CSR build ----------------

__global__ __launch_bounds__(256) void k_deg(const int* __restrict__ dst, int* __restrict__ deg) {
  int e = blockIdx.x * 256 + threadIdx.x;
  if (e < NE) atomicAdd(&deg[dst[e]], 1);
}

__global__ __launch_bounds__(256) void k_dis(const int* __restrict__ deg, float* __restrict__ dis) {
  int i = blockIdx.x * 256 + threadIdx.x;
  if (i < NN) dis[i] = rsqrtf((float)deg[i] + 1.0f);
}

__global__ __launch_bounds__(1024) void k_scan1(const int* __restrict__ deg, int* __restrict__ excl,
                                                int* __restrict__ blksum) {
  __shared__ int sm[1024];
  int t = threadIdx.x;
  int i = blockIdx.x * 1024 + t;
  int v = (i < NN) ? deg[i] : 0;
  sm[t] = v;
  __syncthreads();
  for (int off = 1; off < 1024; off <<= 1) {
    int x = (t >= off) ? sm[t - off] : 0;
    __syncthreads();
    sm[t] += x;
    __syncthreads();
  }
  if (i < NN) excl[i] = sm[t] - v;
  if (t == 1023) blksum[blockIdx.x] = sm[t];
}

__global__ void k_scan2(const int* __restrict__ blksum, int* __restrict__ blkoff,
                        int* __restrict__ rowstart) {
  int t = threadIdx.x;  // 64 threads, one wave
  int orig = (t < NBLK) ? blksum[t] : 0;
  int v = orig;
  #pragma unroll
  for (int off = 1; off < 64; off <<= 1) {
    int u = __shfl_up(v, off);
    if (t >= off) v += u;
  }
  if (t < NBLK) blkoff[t] = v - orig;
  if (t == NBLK - 1) rowstart[NN] = v;  // == NE
}

__global__ __launch_bounds__(256) void k_scan3(int* __restrict__ excl, const int* __restrict__ blkoff) {
  int i = blockIdx.x * 256 + threadIdx.x;
  if (i < NN) excl[i] += blkoff[i >> 10];
}

__global__ __launch_bounds__(256) void k_fill(const int* __restrict__ src, const int* __restrict__ dst,
                                              const int* __restrict__ rowstart, int* __restrict__ cursor,
                                              int* __restrict__ csr_src) {
  int e = blockIdx.x * 256 + threadIdx.x;
  if (e < NE) {
    int d = dst[e];
    int p = atomicAdd(&cursor[d], 1);
    csr_src[rowstart[d] + p] = src[e];
  }
}

// ---------------- SGEMM: H[M,NC] = X[M,128] * W[128,NC] ----------------
// block: 128 rows x NC cols, 256 threads, micro-tile 8 x (NC/16)

template <int NC>
__global__ __launch_bounds__(256) void k_gemm(const float* __restrict__ X, const float* __restrict__ W,
                                              float* __restrict__ H, int M) {
  constexpr int TN = NC / 16;
  __shared__ float As[8][128];
  __shared__ float Bs[8][NC];
  const int tid = threadIdx.x;
  const int rg = tid >> 4;   // 0..15
  const int cg = tid & 15;   // 0..15
  const int row0 = blockIdx.x * 128;

  float acc[8][TN];
  #pragma unroll
  for (int i = 0; i < 8; i++)
    #pragma unroll
    for (int j = 0; j < TN; j++) acc[i][j] = 0.f;

  const int lr = tid >> 1;         // 0..127 row in tile
  const int lk = (tid & 1) * 4;    // 0 or 4

  for (int kt = 0; kt < 128; kt += 8) {
    float4 av = make_float4(0.f, 0.f, 0.f, 0.f);
    int gr = row0 + lr;
    if (gr < M) av = *(const float4*)(X + (size_t)gr * 128 + kt + lk);
    As[lk + 0][lr] = av.x; As[lk + 1][lr] = av.y; As[lk + 2][lr] = av.z; As[lk + 3][lr] = av.w;
    if constexpr (NC == 128) {
      int k = tid >> 5, c = (tid & 31) * 4;
      *(float4*)&Bs[k][c] = *(const float4*)(W + (size_t)(k + kt) * 128 + c);
    } else {  // NC == 32: one float per thread
      int k = tid >> 5, c = tid & 31;
      Bs[k][c] = W[(size_t)(k + kt) * NC + c];
    }
    __syncthreads();
    #pragma unroll
    for (int kk = 0; kk < 8; kk++) {
      float a[8];
      *(float4*)&a[0] = *(const float4*)&As[kk][rg * 8];
      *(float4*)&a[4] = *(const float4*)&As[kk][rg * 8 + 4];
      float b[TN];
      if constexpr (TN == 8) {
        *(float4*)&b[0] = *(const float4*)&Bs[kk][cg * 8];
        *(float4*)&b[4] = *(const float4*)&Bs[kk][cg * 8 + 4];
      } else {
        b[0] = Bs[kk][cg * 2]; b[1] = Bs[kk][cg * 2 + 1];
      }
      #pragma unroll
      for (int i = 0; i < 8; i++)
        #pragma unroll
        for (int j = 0; j < TN; j++) acc[i][j] += a[i] * b[j];
    }
    __syncthreads();
  }

  #pragma unroll
  for (int i = 0; i < 8; i++) {
    int gr = row0 + rg * 8 + i;
    if (gr < M) {
      if constexpr (TN == 8) {
        *(float4*)(H + (size_t)gr * NC + cg * 8)     = make_float4(acc[i][0], acc[i][1], acc[i][2], acc[i][3]);
        *(float4*)(H + (size_t)gr * NC + cg * 8 + 4) = make_float4(acc[i][4], acc[i][5], acc[i][6], acc[i][7]);
      } else {
        *(float2*)(H + (size_t)gr * NC + cg * 2) = make_float2(acc[i][0], acc[i][1]);
      }
    }
  }
}

// ---------------- aggregation: one wave per node, atomic-free ----------------

__global__ __launch_bounds__(256) void k_agg128(const float* __restrict__ H, const float* __restrict__ dis,
                                                const int* __restrict__ rowstart, const int* __restrict__ csr_src,
                                                const float* __restrict__ bias, float* __restrict__ out) {
  int w = (blockIdx.x * 256 + threadIdx.x) >> 6;
  int lane = threadIdx.x & 63;
  if (w >= NN) return;
  float di = dis[w];
  int e0 = rowstart[w], e1 = rowstart[w + 1];
  float2 acc = make_float2(0.f, 0.f);
  for (int e = e0; e < e1; e++) {
    int s = csr_src[e];
    float nrm = dis[s] * di;
    float2 hv = *(const float2*)(H + (size_t)s * 128 + lane * 2);
    acc.x += hv.x * nrm;
    acc.y += hv.y * nrm;
  }
  float2 hv = *(const float2*)(H + (size_t)w * 128 + lane * 2);
  float sn = di * di;
  acc.x += hv.x * sn + bias[lane * 2];
  acc.y += hv.y * sn + bias[lane * 2 + 1];
  *(float2*)(out + (size_t)w * 128 + lane * 2) = acc;
}

__global__ __launch_bounds__(256) void k_agg32(const float* __restrict__ H, const float* __restrict__ dis,
                                               const int* __restrict__ rowstart, const int* __restrict__ csr_src,
                                               const float* __restrict__ bias, float* __restrict__ out) {
  int w = (blockIdx.x * 256 + threadIdx.x) >> 6;
  int lane = threadIdx.x & 63;
  if (w >= NN || lane >= 32) return;
  float di = dis[w];
  int e1 = rowstart[w + 1];
  float acc = 0.f;
  for (int e = rowstart[w]; e < e1; e++) {
    int s = csr_src[e];
    acc += H[(size_t)s * 32 + lane] * (dis[s] * di);
  }
  acc += H[(size_t)w * 32 + lane] * (di * di) + bias[lane];
  out[(size_t)w * 32 + lane] = acc;
}

// ---------------- BatchNorm stats + fused BN/ReLU/residual ----------------

__global__ __launch_bounds__(256) void k_bnstats(const float* __restrict__ O, float* __restrict__ gsum,
                                                 float* __restrict__ gsumsq) {
  int tid = threadIdx.x;
  int f = tid & 127;
  int half = tid >> 7;
  float s = 0.f, sq = 0.f;
  for (int r = blockIdx.x * 2 + half; r < NN; r += gridDim.x * 2) {
    float v = O[(size_t)r * 128 + f];
    s += v; sq += v * v;
  }
  __shared__ float sm[256], sm2[256];
  sm[tid] = s; sm2[tid] = sq;
  __syncthreads();
  if (tid < 128) {
    atomicAdd(&gsum[f], sm[tid] + sm[tid + 128]);
    atomicAdd(&gsumsq[f], sm2[tid] + sm2[tid + 128]);
  }
}

__global__ void k_bnfinal(const float* __restrict__ gsum, const float* __restrict__ gsumsq,
                          float* __restrict__ mu, float* __restrict__ istd) {
  int f = threadIdx.x;  // 128
  float m = gsum[f] / (float)NN;
  float v = gsumsq[f] / (float)NN - m * m;
  mu[f] = m;
  istd[f] = rsqrtf(v + 1e-5f);
}

// Xout[i] = relu((O[i]-mu)*istd*g + be) + Xin[i]   (safe when Xin==Xout)
__global__ __launch_bounds__(256) void k_fuse(const float* __restrict__ O, const float* Xin, float* Xout,
                                              const float* __restrict__ mu, const float* __restrict__ istd,
                                              const float* __restrict__ g, const float* __restrict__ be) {
  int i = blockIdx.x * 256 + threadIdx.x;
  if (i >= NN * 128 / 4) return;
  int f = (i * 4) & 127;
  float4 ov = ((const float4*)O)[i];
  float4 xv = ((const float4*)Xin)[i];
  float4 r;
  r.x = fmaxf((ov.x - mu[f + 0]) * istd[f + 0] * g[f + 0] + be[f + 0], 0.f) + xv.x;
  r.y = fmaxf((ov.y - mu[f + 1]) * istd[f + 1] * g[f + 1] + be[f + 1], 0.f) + xv.y;
  r.z = fmaxf((ov.z - mu[f + 2]) * istd[f + 2] * g[f + 2] + be[f + 2], 0.f) + xv.z;
  r.w = fmaxf((ov.w - mu[f + 3]) * istd[f + 3] * g[f + 3] + be[f + 3], 0.f) + xv.w;
  ((float4*)Xout)[i] = r;
}

// ---------------- log_softmax over 32 classes, in-place ----------------

__global__ __launch_bounds__(256) void k_lsm(float* __restrict__ out) {
  int w = (blockIdx.x * 256 + threadIdx.x) >> 6;
  int lane = threadIdx.x & 63;
  if (w >= NN) return;
  float v = (lane < 32) ? out[(size_t)w * 32 + lane] : -1e30f;
  float m = v;
  #pragma unroll
  for (int off = 16; off >= 1; off >>= 1) m = fmaxf(m, __shfl_xor(m, off));
  float e = (lane < 32) ? expf(v - m) : 0.f;
  float s = e;
  #pragma unroll
  for (int off = 16; off >= 1; off >>= 1) s += __shfl_xor(s, off);
  if (lane < 32) out[(size_t)w * 32 + lane] = v - m - logf(s);
}

// ---------------- launch ----------------

extern "C" void kernel_launch(void* const* d_in, const int* in_sizes, int n_in,
                              void* d_out, int out_size, void* d_ws, size_t ws_size,
                              hipStream_t stream) {
  const float* x   = (const float*)d_in[0];
  const int*   ei  = (const int*)d_in[1];
  const float* W0  = (const float*)d_in[2];
  const float* b0  = (const float*)d_in[3];
  const float* g0  = (const float*)d_in[4];
  const float* be0 = (const float*)d_in[5];
  const float* W1  = (const float*)d_in[6];
  const float* b1  = (const float*)d_in[7];
  const float* g1  = (const float*)d_in[8];
  const float* be1 = (const float*)d_in[9];
  const float* W2  = (const float*)d_in[10];
  const float* b2  = (const float*)d_in[11];
  float* out = (float*)d_out;
  const int* srcI = ei;
  const int* dstI = ei + NE;

  char* p = (char*)d_ws;
  auto take = [&](size_t bytes) { char* r = p; p += (bytes + 255) & ~(size_t)255; return (void*)r; };
  int*   deg      = (int*)take(NN * 4);
  int*   cursor   = (int*)take(NN * 4);
  int*   rowstart = (int*)take((NN + 1) * 4);
  int*   blksum   = (int*)take(64 * 4);
  int*   blkoff   = (int*)take(64 * 4);
  float* dis      = (float*)take(NN * 4);
  int*   csr      = (int*)take(NE * 4);
  float* gstat    = (float*)take(256 * 4);  // gsum[128] | gsumsq[128]
  float* mu       = (float*)take(128 * 4);
  float* istd     = (float*)take(128 * 4);
  float* h        = (float*)take((size_t)NN * 128 * 4);
  float* o        = (float*)take((size_t)NN * 128 * 4);
  float* xA       = (float*)take((size_t)NN * 128 * 4);
  float* h2       = (float*)take((size_t)NN * 32 * 4);

  hipMemsetAsync(deg, 0, NN * 4, stream);
  hipMemsetAsync(cursor, 0, NN * 4, stream);

  k_deg<<<(NE + 255) / 256, 256, 0, stream>>>(dstI, deg);
  k_dis<<<(NN + 255) / 256, 256, 0, stream>>>(deg, dis);
  k_scan1<<<NBLK, 1024, 0, stream>>>(deg, rowstart, blksum);
  k_scan2<<<1, 64, 0, stream>>>(blksum, blkoff, rowstart);
  k_scan3<<<(NN + 255) / 256, 256, 0, stream>>>(rowstart, blkoff);
  k_fill<<<(NE + 255) / 256, 256, 0, stream>>>(srcI, dstI, rowstart, cursor, csr);

  // ---- layer 0 ----
  k_gemm<128><<<(NN + 127) / 128, 256, 0, stream>>>(x, W0, h, NN);
  k_agg128<<<(NN + 3) / 4, 256, 0, stream>>>(h, dis, rowstart, csr, b0, o);
  hipMemsetAsync(gstat, 0, 256 * 4, stream);
  k_bnstats<<<256, 256, 0, stream>>>(o, gstat, gstat + 128);
  k_bnfinal<<<1, 128, 0, stream>>>(gstat, gstat + 128, mu, istd);
  k_fuse<<<(NN * 128 / 4 + 255) / 256, 256, 0, stream>>>(o, x, xA, mu, istd, g0, be0);

  // ---- layer 1 ----
  k_gemm<128><<<(NN + 127) / 128, 256, 0, stream>>>(xA, W1, h, NN);
  k_agg128<<<(NN + 3) / 4, 256, 0, stream>>>(h, dis, rowstart, csr, b1, o);
  hipMemsetAsync(gstat, 0, 256 * 4, stream);
  k_bnstats<<<256, 256, 0, stream>>>(o, gstat, gstat + 128);
  k_bnfinal<<<1, 128, 0, stream>>>(gstat, gstat + 128, mu, istd);
  k_fuse<<<(NN * 128 / 4 + 255) / 256, 256, 0, stream>>>(o, xA, xA, mu, istd, g1, be1);

  // ---- final conv + log_softmax ----
  k_gemm<32><<<(NN + 127) / 128, 256, 0, stream>>>(xA, W2, h2, NN);
  k_agg32<<<(NN + 3) / 4, 256, 0, stream>>>(h2, dis, rowstart, csr, b2, out);
  k_lsm<<<(NN + 3) / 4, 256, 0, stream>>>(out);
}

// Round 2
// 497.201 us; speedup vs baseline: 1.2404x; 1.2404x over previous
//
#include <hip/hip_runtime.h>
#include <math.h>

#define NN 50000
#define NE 800000
#define NBLK 49   // ceil(NN/1024)

// ---------------- degree / CSR build ----------------

__global__ __launch_bounds__(256) void k_deg(const int* __restrict__ dst, int* __restrict__ deg) {
  int e = blockIdx.x * 256 + threadIdx.x;
  if (e < NE) atomicAdd(&deg[dst[e]], 1);
}

__global__ __launch_bounds__(1024) void k_scan1(const int* __restrict__ deg, int* __restrict__ excl,
                                                int* __restrict__ blksum) {
  __shared__ int sm[1024];
  int t = threadIdx.x;
  int i = blockIdx.x * 1024 + t;
  int v = (i < NN) ? deg[i] : 0;
  sm[t] = v;
  __syncthreads();
  for (int off = 1; off < 1024; off <<= 1) {
    int x = (t >= off) ? sm[t - off] : 0;
    __syncthreads();
    sm[t] += x;
    __syncthreads();
  }
  if (i < NN) excl[i] = sm[t] - v;
  if (t == 1023) blksum[blockIdx.x] = sm[t];
}

__global__ void k_scan2(const int* __restrict__ blksum, int* __restrict__ blkoff,
                        int* __restrict__ rowstart) {
  int t = threadIdx.x;  // 64 threads, one wave
  int orig = (t < NBLK) ? blksum[t] : 0;
  int v = orig;
  #pragma unroll
  for (int off = 1; off < 64; off <<= 1) {
    int u = __shfl_up(v, off);
    if (t >= off) v += u;
  }
  if (t < NBLK) blkoff[t] = v - orig;
  if (t == NBLK - 1) rowstart[NN] = v;  // == NE
}

// also computes dis[] (folded former k_dis)
__global__ __launch_bounds__(256) void k_scan3(int* __restrict__ excl, const int* __restrict__ blkoff,
                                               const int* __restrict__ deg, float* __restrict__ dis) {
  int i = blockIdx.x * 256 + threadIdx.x;
  if (i < NN) {
    excl[i] += blkoff[i >> 10];
    dis[i] = rsqrtf((float)deg[i] + 1.0f);
  }
}

__global__ __launch_bounds__(256) void k_fill(const int* __restrict__ src, const int* __restrict__ dst,
                                              const int* __restrict__ rowstart, int* __restrict__ cursor,
                                              int* __restrict__ csr_src) {
  int e = blockIdx.x * 256 + threadIdx.x;
  if (e < NE) {
    int d = dst[e];
    int p = atomicAdd(&cursor[d], 1);
    csr_src[rowstart[d] + p] = src[e];
  }
}

// ---------------- SGEMM: H[M,NC] = X[M,128] * W[128,NC] ----------------

template <int NC>
__global__ __launch_bounds__(256) void k_gemm(const float* __restrict__ X, const float* __restrict__ W,
                                              float* __restrict__ H, int M) {
  constexpr int TN = NC / 16;
  __shared__ float As[8][128];
  __shared__ float Bs[8][NC];
  const int tid = threadIdx.x;
  const int rg = tid >> 4;   // 0..15
  const int cg = tid & 15;   // 0..15
  const int row0 = blockIdx.x * 128;

  float acc[8][TN];
  #pragma unroll
  for (int i = 0; i < 8; i++)
    #pragma unroll
    for (int j = 0; j < TN; j++) acc[i][j] = 0.f;

  const int lr = tid >> 1;         // 0..127 row in tile
  const int lk = (tid & 1) * 4;    // 0 or 4

  for (int kt = 0; kt < 128; kt += 8) {
    float4 av = make_float4(0.f, 0.f, 0.f, 0.f);
    int gr = row0 + lr;
    if (gr < M) av = *(const float4*)(X + (size_t)gr * 128 + kt + lk);
    As[lk + 0][lr] = av.x; As[lk + 1][lr] = av.y; As[lk + 2][lr] = av.z; As[lk + 3][lr] = av.w;
    if constexpr (NC == 128) {
      int k = tid >> 5, c = (tid & 31) * 4;
      *(float4*)&Bs[k][c] = *(const float4*)(W + (size_t)(k + kt) * 128 + c);
    } else {  // NC == 32
      int k = tid >> 5, c = tid & 31;
      Bs[k][c] = W[(size_t)(k + kt) * NC + c];
    }
    __syncthreads();
    #pragma unroll
    for (int kk = 0; kk < 8; kk++) {
      float a[8];
      *(float4*)&a[0] = *(const float4*)&As[kk][rg * 8];
      *(float4*)&a[4] = *(const float4*)&As[kk][rg * 8 + 4];
      float b[TN];
      if constexpr (TN == 8) {
        *(float4*)&b[0] = *(const float4*)&Bs[kk][cg * 8];
        *(float4*)&b[4] = *(const float4*)&Bs[kk][cg * 8 + 4];
      } else {
        b[0] = Bs[kk][cg * 2]; b[1] = Bs[kk][cg * 2 + 1];
      }
      #pragma unroll
      for (int i = 0; i < 8; i++)
        #pragma unroll
        for (int j = 0; j < TN; j++) acc[i][j] += a[i] * b[j];
    }
    __syncthreads();
  }

  #pragma unroll
  for (int i = 0; i < 8; i++) {
    int gr = row0 + rg * 8 + i;
    if (gr < M) {
      if constexpr (TN == 8) {
        *(float4*)(H + (size_t)gr * NC + cg * 8)     = make_float4(acc[i][0], acc[i][1], acc[i][2], acc[i][3]);
        *(float4*)(H + (size_t)gr * NC + cg * 8 + 4) = make_float4(acc[i][4], acc[i][5], acc[i][6], acc[i][7]);
      } else {
        *(float2*)(H + (size_t)gr * NC + cg * 2) = make_float2(acc[i][0], acc[i][1]);
      }
    }
  }
}

// ---------------- aggregation: one wave per node, MLP-batched ----------------
// Edge indices + dis[] pre-gathered lane-parallel per 64-edge chunk, then
// broadcast via shuffles; row gathers unrolled x4 for memory-level parallelism.

__global__ __launch_bounds__(256) void k_agg128(const float* __restrict__ H, const float* __restrict__ dis,
                                                const int* __restrict__ rowstart, const int* __restrict__ csr_src,
                                                const float* __restrict__ bias, float* __restrict__ out) {
  int w = (blockIdx.x * 256 + threadIdx.x) >> 6;
  int lane = threadIdx.x & 63;
  if (w >= NN) return;
  float di = dis[w];
  int e0 = rowstart[w], e1 = rowstart[w + 1];
  float2 acc = make_float2(0.f, 0.f);

  for (int base = e0; base < e1; base += 64) {
    int cnt = e1 - base; if (cnt > 64) cnt = 64;
    int myS = 0; float myN = 0.f;
    if (base + lane < e1) {
      myS = csr_src[base + lane];
      myN = dis[myS];
    }
    int j = 0;
    for (; j + 4 <= cnt; j += 4) {
      int s0 = __shfl(myS, j),     s1 = __shfl(myS, j + 1);
      int s2 = __shfl(myS, j + 2), s3 = __shfl(myS, j + 3);
      float n0 = __shfl(myN, j),     n1 = __shfl(myN, j + 1);
      float n2 = __shfl(myN, j + 2), n3 = __shfl(myN, j + 3);
      float2 h0 = *(const float2*)(H + (size_t)s0 * 128 + lane * 2);
      float2 h1 = *(const float2*)(H + (size_t)s1 * 128 + lane * 2);
      float2 h2 = *(const float2*)(H + (size_t)s2 * 128 + lane * 2);
      float2 h3 = *(const float2*)(H + (size_t)s3 * 128 + lane * 2);
      acc.x += h0.x * n0; acc.y += h0.y * n0;
      acc.x += h1.x * n1; acc.y += h1.y * n1;
      acc.x += h2.x * n2; acc.y += h2.y * n2;
      acc.x += h3.x * n3; acc.y += h3.y * n3;
    }
    for (; j < cnt; j++) {
      int s = __shfl(myS, j);
      float n = __shfl(myN, j);
      float2 hv = *(const float2*)(H + (size_t)s * 128 + lane * 2);
      acc.x += hv.x * n; acc.y += hv.y * n;
    }
  }
  // acc held sum of h[s]*dis[s]; scale by di once, then self-loop + bias
  float2 hv = *(const float2*)(H + (size_t)w * 128 + lane * 2);
  float sn = di * di;
  acc.x = acc.x * di + hv.x * sn + bias[lane * 2];
  acc.y = acc.y * di + hv.y * sn + bias[lane * 2 + 1];
  *(float2*)(out + (size_t)w * 128 + lane * 2) = acc;
}

// 2 nodes per wave (halves of the wave), 32-wide shuffle broadcast
__global__ __launch_bounds__(256) void k_agg32(const float* __restrict__ H, const float* __restrict__ dis,
                                               const int* __restrict__ rowstart, const int* __restrict__ csr_src,
                                               const float* __restrict__ bias, float* __restrict__ out) {
  int pair = (blockIdx.x * 256 + threadIdx.x) >> 6;  // wave id
  int lane = threadIdx.x & 63;
  int half = lane >> 5;                               // 0/1: which node
  int l    = lane & 31;
  int w = pair * 2 + half;
  if (w >= NN) return;
  float di = dis[w];
  int e0 = rowstart[w], e1 = rowstart[w + 1];
  float acc = 0.f;

  for (int base = e0; base < e1; base += 32) {
    int cnt = e1 - base; if (cnt > 32) cnt = 32;
    int myS = 0; float myN = 0.f;
    if (base + l < e1) {
      myS = csr_src[base + l];
      myN = dis[myS];
    }
    int j = 0;
    for (; j + 4 <= cnt; j += 4) {
      int s0 = __shfl(myS, j, 32),     s1 = __shfl(myS, j + 1, 32);
      int s2 = __shfl(myS, j + 2, 32), s3 = __shfl(myS, j + 3, 32);
      float n0 = __shfl(myN, j, 32),     n1 = __shfl(myN, j + 1, 32);
      float n2 = __shfl(myN, j + 2, 32), n3 = __shfl(myN, j + 3, 32);
      float h0 = H[(size_t)s0 * 32 + l];
      float h1 = H[(size_t)s1 * 32 + l];
      float h2 = H[(size_t)s2 * 32 + l];
      float h3 = H[(size_t)s3 * 32 + l];
      acc += h0 * n0 + h1 * n1 + h2 * n2 + h3 * n3;
    }
    for (; j < cnt; j++) {
      int s = __shfl(myS, j, 32);
      float n = __shfl(myN, j, 32);
      acc += H[(size_t)s * 32 + l] * n;
    }
  }
  acc = acc * di + H[(size_t)w * 32 + l] * (di * di) + bias[l];
  out[(size_t)w * 32 + l] = acc;
}

// ---------------- BatchNorm stats + fused BN/ReLU/residual ----------------

__global__ __launch_bounds__(256) void k_bnstats(const float* __restrict__ O, float* __restrict__ gsum,
                                                 float* __restrict__ gsumsq) {
  int tid = threadIdx.x;
  int f = tid & 127;
  int half = tid >> 7;
  float s = 0.f, sq = 0.f;
  for (int r = blockIdx.x * 2 + half; r < NN; r += gridDim.x * 2) {
    float v = O[(size_t)r * 128 + f];
    s += v; sq += v * v;
  }
  __shared__ float sm[256], sm2[256];
  sm[tid] = s; sm2[tid] = sq;
  __syncthreads();
  if (tid < 128) {
    atomicAdd(&gsum[f], sm[tid] + sm[tid + 128]);
    atomicAdd(&gsumsq[f], sm2[tid] + sm2[tid + 128]);
  }
}

__global__ void k_bnfinal(const float* __restrict__ gsum, const float* __restrict__ gsumsq,
                          float* __restrict__ mu, float* __restrict__ istd) {
  int f = threadIdx.x;  // 128
  float m = gsum[f] / (float)NN;
  float v = gsumsq[f] / (float)NN - m * m;
  mu[f] = m;
  istd[f] = rsqrtf(v + 1e-5f);
}

__global__ __launch_bounds__(256) void k_fuse(const float* __restrict__ O, const float* Xin, float* Xout,
                                              const float* __restrict__ mu, const float* __restrict__ istd,
                                              const float* __restrict__ g, const float* __restrict__ be) {
  int i = blockIdx.x * 256 + threadIdx.x;
  if (i >= NN * 128 / 4) return;
  int f = (i * 4) & 127;
  float4 ov = ((const float4*)O)[i];
  float4 xv = ((const float4*)Xin)[i];
  float4 r;
  r.x = fmaxf((ov.x - mu[f + 0]) * istd[f + 0] * g[f + 0] + be[f + 0], 0.f) + xv.x;
  r.y = fmaxf((ov.y - mu[f + 1]) * istd[f + 1] * g[f + 1] + be[f + 1], 0.f) + xv.y;
  r.z = fmaxf((ov.z - mu[f + 2]) * istd[f + 2] * g[f + 2] + be[f + 2], 0.f) + xv.z;
  r.w = fmaxf((ov.w - mu[f + 3]) * istd[f + 3] * g[f + 3] + be[f + 3], 0.f) + xv.w;
  ((float4*)Xout)[i] = r;
}

// ---------------- log_softmax over 32 classes, in-place ----------------

__global__ __launch_bounds__(256) void k_lsm(float* __restrict__ out) {
  int w = (blockIdx.x * 256 + threadIdx.x) >> 6;
  int lane = threadIdx.x & 63;
  if (w >= NN) return;
  float v = (lane < 32) ? out[(size_t)w * 32 + lane] : -1e30f;
  float m = v;
  #pragma unroll
  for (int off = 16; off >= 1; off >>= 1) m = fmaxf(m, __shfl_xor(m, off));
  float e = (lane < 32) ? expf(v - m) : 0.f;
  float s = e;
  #pragma unroll
  for (int off = 16; off >= 1; off >>= 1) s += __shfl_xor(s, off);
  if (lane < 32) out[(size_t)w * 32 + lane] = v - m - logf(s);
}

// ---------------- launch ----------------

extern "C" void kernel_launch(void* const* d_in, const int* in_sizes, int n_in,
                              void* d_out, int out_size, void* d_ws, size_t ws_size,
                              hipStream_t stream) {
  const float* x   = (const float*)d_in[0];
  const int*   ei  = (const int*)d_in[1];
  const float* W0  = (const float*)d_in[2];
  const float* b0  = (const float*)d_in[3];
  const float* g0  = (const float*)d_in[4];
  const float* be0 = (const float*)d_in[5];
  const float* W1  = (const float*)d_in[6];
  const float* b1  = (const float*)d_in[7];
  const float* g1  = (const float*)d_in[8];
  const float* be1 = (const float*)d_in[9];
  const float* W2  = (const float*)d_in[10];
  const float* b2  = (const float*)d_in[11];
  float* out = (float*)d_out;
  const int* srcI = ei;
  const int* dstI = ei + NE;

  char* p = (char*)d_ws;
  auto take = [&](size_t bytes) { char* r = p; p += (bytes + 255) & ~(size_t)255; return (void*)r; };
  int*   deg      = (int*)take(NN * 4);
  int*   cursor   = (int*)take(NN * 4);
  int*   rowstart = (int*)take((NN + 1) * 4);
  int*   blksum   = (int*)take(64 * 4);
  int*   blkoff   = (int*)take(64 * 4);
  float* dis      = (float*)take(NN * 4);
  int*   csr      = (int*)take(NE * 4);
  float* gstat    = (float*)take(256 * 4);
  float* mu       = (float*)take(128 * 4);
  float* istd     = (float*)take(128 * 4);
  float* h        = (float*)take((size_t)NN * 128 * 4);
  float* o        = (float*)take((size_t)NN * 128 * 4);
  float* xA       = (float*)take((size_t)NN * 128 * 4);
  float* h2       = (float*)take((size_t)NN * 32 * 4);

  hipMemsetAsync(deg, 0, NN * 4, stream);
  hipMemsetAsync(cursor, 0, NN * 4, stream);

  k_deg<<<(NE + 255) / 256, 256, 0, stream>>>(dstI, deg);
  k_scan1<<<NBLK, 1024, 0, stream>>>(deg, rowstart, blksum);
  k_scan2<<<1, 64, 0, stream>>>(blksum, blkoff, rowstart);
  k_scan3<<<(NN + 255) / 256, 256, 0, stream>>>(rowstart, blkoff, deg, dis);
  k_fill<<<(NE + 255) / 256, 256, 0, stream>>>(srcI, dstI, rowstart, cursor, csr);

  // ---- layer 0 ----
  k_gemm<128><<<(NN + 127) / 128, 256, 0, stream>>>(x, W0, h, NN);
  k_agg128<<<(NN + 3) / 4, 256, 0, stream>>>(h, dis, rowstart, csr, b0, o);
  hipMemsetAsync(gstat, 0, 256 * 4, stream);
  k_bnstats<<<256, 256, 0, stream>>>(o, gstat, gstat + 128);
  k_bnfinal<<<1, 128, 0, stream>>>(gstat, gstat + 128, mu, istd);
  k_fuse<<<(NN * 128 / 4 + 255) / 256, 256, 0, stream>>>(o, x, xA, mu, istd, g0, be0);

  // ---- layer 1 ----
  k_gemm<128><<<(NN + 127) / 128, 256, 0, stream>>>(xA, W1, h, NN);
  k_agg128<<<(NN + 3) / 4, 256, 0, stream>>>(h, dis, rowstart, csr, b1, o);
  hipMemsetAsync(gstat, 0, 256 * 4, stream);
  k_bnstats<<<256, 256, 0, stream>>>(o, gstat, gstat + 128);
  k_bnfinal<<<1, 128, 0, stream>>>(gstat, gstat + 128, mu, istd);
  k_fuse<<<(NN * 128 / 4 + 255) / 256, 256, 0, stream>>>(o, xA, xA, mu, istd, g1, be1);

  // ---- final conv + log_softmax ----
  k_gemm<32><<<(NN + 127) / 128, 256, 0, stream>>>(xA, W2, h2, NN);
  k_agg32<<<(NN + 3) / 4, 256, 0, stream>>>(h2, dis, rowstart, csr, b2, out);
  k_lsm<<<(NN + 3) / 4, 256, 0, stream>>>(out);
}